// Round 3
// baseline (2244.011 us; speedup 1.0000x reference)
//
#include <hip/hip_runtime.h>

#define M_DIM 8192
#define K_DIM 4096
#define N_DIM 16384
#define KT 64   // K_DIM / 64 K-tiles

typedef unsigned short u16;
typedef __attribute__((ext_vector_type(8))) unsigned short ushort8;
typedef __attribute__((ext_vector_type(8))) short short8;
typedef __attribute__((ext_vector_type(4))) float f32x4;

// fp32 -> bf16 round-to-nearest-even
__device__ __forceinline__ u16 f2b(float f) {
  union { float f; unsigned u; } v; v.f = f;
  unsigned r = (v.u + 0x7fffu + ((v.u >> 16) & 1u)) >> 16;
  return (u16)r;
}

// ---- pre-pass 1: x fp32 -> bf16 ------------------------------------------
__global__ void cvt_x_kernel(const float* __restrict__ x, u16* __restrict__ xb, int n8) {
  int i = blockIdx.x * blockDim.x + threadIdx.x;
  const int stride = gridDim.x * blockDim.x;
  const float4* xf = reinterpret_cast<const float4*>(x);
  ushort8* o = reinterpret_cast<ushort8*>(xb);
  for (; i < n8; i += stride) {
    float4 a = xf[2 * i], b = xf[2 * i + 1];
    ushort8 r;
    r[0] = f2b(a.x); r[1] = f2b(a.y); r[2] = f2b(a.z); r[3] = f2b(a.w);
    r[4] = f2b(b.x); r[5] = f2b(b.y); r[6] = f2b(b.z); r[7] = f2b(b.w);
    o[i] = r;
  }
}

// ---- pre-pass 2: w_q int32 * block scale -> bf16 -------------------------
__global__ void dequant_w_kernel(const int* __restrict__ wq, const float* __restrict__ wsc,
                                 u16* __restrict__ wb, int n8) {
  int i = blockIdx.x * blockDim.x + threadIdx.x;
  const int stride = gridDim.x * blockDim.x;
  const int4* q = reinterpret_cast<const int4*>(wq);
  ushort8* o = reinterpret_cast<ushort8*>(wb);
  for (; i < n8; i += stride) {
    int n = i >> 9;
    int k8 = i & 511;
    float s = wsc[(n >> 7) * (K_DIM / 128) + (k8 >> 4)];
    int4 a = q[2 * i], b = q[2 * i + 1];
    ushort8 r;
    r[0] = f2b((float)a.x * s); r[1] = f2b((float)a.y * s);
    r[2] = f2b((float)a.z * s); r[3] = f2b((float)a.w * s);
    r[4] = f2b((float)b.x * s); r[5] = f2b((float)b.y * s);
    r[6] = f2b((float)b.z * s); r[7] = f2b((float)b.w * s);
    o[i] = r;
  }
}

// ---- async global -> LDS, 16 B per lane (dest = wave base + lane*16) -----
__device__ __forceinline__ void gload16(const void* g, void* l) {
  __builtin_amdgcn_global_load_lds(
      (const __attribute__((address_space(1))) unsigned int*)g,
      (__attribute__((address_space(3))) unsigned int*)l, 16, 0, 0);
}

#define BAR() do { asm volatile("" ::: "memory"); \
                   __builtin_amdgcn_s_barrier();  \
                   asm volatile("" ::: "memory"); } while (0)

#define MF(a, b, c) __builtin_amdgcn_mfma_f32_16x16x32_bf16(a, b, c, 0, 0, 0)

// ---- 256x256x64 8-wave pipelined GEMM: C = A[M,K] * B[N,K]^T + bias ------
// Register-double-banked fragments: phase q issues ds_reads for quad q+1,
// computes quad q from frags issued one phase earlier (LDS service overlaps
// the MFMA burst). B-frags + next-tile A-quad0 prefetched at phase 3 after
// the counted vmcnt + barrier.
__global__ __launch_bounds__(512, 2) void gemm_kernel(
    const u16* __restrict__ A, const u16* __restrict__ B,
    const float* __restrict__ bias, float* __restrict__ C) {
  __shared__ __align__(128) char lds[131072];  // 2 bufs x (A 32K + B 32K)

  const int tid = threadIdx.x;
  const int lane = tid & 63, wid = tid >> 6;
  const int wr = wid >> 2, wc = wid & 3;    // 2 x 4 wave grid

  // XCD-bijective swizzle: 2048 blocks, 8 XCDs, 256 per XCD
  const int bid = blockIdx.x;
  const int swz = (bid & 7) * 256 + (bid >> 3);
  const int tm = swz >> 6, tn = swz & 63;   // 32 x 64 tiles

  // staging: per-lane pre-swizzled global source, linear LDS dest
  const int srow = (wid << 3) + (lane >> 3);
  const int kswz = ((lane & 7) ^ ((lane >> 3) & 7)) << 3;
  const u16* aSrc = A + (size_t)(tm * 256 + srow) * K_DIM + kswz;
  const u16* bSrc = B + (size_t)(tn * 256 + srow) * K_DIM + kswz;
  const int ldst = wid << 10;

#define STAGE_A(tt, h, s, b) gload16(aSrc + (size_t)((h)*128 + (s)*64) * K_DIM + (size_t)(tt)*64, \
                                     lds + (b)*65536 + (h)*16384 + (s)*8192 + ldst)
#define STAGE_B(tt, h, s, b) gload16(bSrc + (size_t)((h)*128 + (s)*64) * K_DIM + (size_t)(tt)*64, \
                                     lds + (b)*65536 + 32768 + (h)*16384 + (s)*8192 + ldst)

  // fragment read addressing (swizzled)
  const int hi = lane >> 4, lo3 = lane & 7;
  const int ak0 = ((0 + hi) ^ lo3) << 4;   // kk elements 0..31, 16B units
  const int ak1 = ((4 + hi) ^ lo3) << 4;   // kk elements 32..63
  const int aoff = (wr * 128 + (lane & 15)) * 128;
  const int boff = 32768 + (wc * 64 + (lane & 15)) * 128;

#define RD_A(D0, D1, D2, D3, base, q) \
  D0 = *(const short8*)((base) + (2*(q)    ) * 2048 + ak0); \
  D1 = *(const short8*)((base) + (2*(q)    ) * 2048 + ak1); \
  D2 = *(const short8*)((base) + (2*(q) + 1) * 2048 + ak0); \
  D3 = *(const short8*)((base) + (2*(q) + 1) * 2048 + ak1);

#define RD_B(P, base) \
  P##00 = *(const short8*)((base) + 0 * 2048 + ak0); \
  P##01 = *(const short8*)((base) + 0 * 2048 + ak1); \
  P##10 = *(const short8*)((base) + 1 * 2048 + ak0); \
  P##11 = *(const short8*)((base) + 1 * 2048 + ak1); \
  P##20 = *(const short8*)((base) + 2 * 2048 + ak0); \
  P##21 = *(const short8*)((base) + 2 * 2048 + ak1); \
  P##30 = *(const short8*)((base) + 3 * 2048 + ak0); \
  P##31 = *(const short8*)((base) + 3 * 2048 + ak1);

// quad q: kk0 updates first (8 independent), then kk1 (dep distance 8)
#define QUADM(q, A0_, A1_, A2_, A3_, P) \
  __builtin_amdgcn_s_setprio(1); \
  acc[2*(q)][0]   = MF(A0_, P##00, acc[2*(q)][0]); \
  acc[2*(q)][1]   = MF(A0_, P##10, acc[2*(q)][1]); \
  acc[2*(q)][2]   = MF(A0_, P##20, acc[2*(q)][2]); \
  acc[2*(q)][3]   = MF(A0_, P##30, acc[2*(q)][3]); \
  acc[2*(q)+1][0] = MF(A2_, P##00, acc[2*(q)+1][0]); \
  acc[2*(q)+1][1] = MF(A2_, P##10, acc[2*(q)+1][1]); \
  acc[2*(q)+1][2] = MF(A2_, P##20, acc[2*(q)+1][2]); \
  acc[2*(q)+1][3] = MF(A2_, P##30, acc[2*(q)+1][3]); \
  acc[2*(q)][0]   = MF(A1_, P##01, acc[2*(q)][0]); \
  acc[2*(q)][1]   = MF(A1_, P##11, acc[2*(q)][1]); \
  acc[2*(q)][2]   = MF(A1_, P##21, acc[2*(q)][2]); \
  acc[2*(q)][3]   = MF(A1_, P##31, acc[2*(q)][3]); \
  acc[2*(q)+1][0] = MF(A3_, P##01, acc[2*(q)+1][0]); \
  acc[2*(q)+1][1] = MF(A3_, P##11, acc[2*(q)+1][1]); \
  acc[2*(q)+1][2] = MF(A3_, P##21, acc[2*(q)+1][2]); \
  acc[2*(q)+1][3] = MF(A3_, P##31, acc[2*(q)+1][3]); \
  __builtin_amdgcn_s_setprio(0);

  f32x4 acc[8][4] = {};
  short8 xa0, xa1, xa2, xa3, ya0, ya1, ya2, ya3;
  short8 bx00, bx01, bx10, bx11, bx20, bx21, bx30, bx31;
  short8 by00, by01, by10, by11, by20, by21, by30, by31;

  // ---- prologue: stage tiles 0 (buf0) and 1 (buf1) ----------------------
  STAGE_A(0, 0, 0, 0); STAGE_A(0, 0, 1, 0); STAGE_A(0, 1, 0, 0); STAGE_A(0, 1, 1, 0);
  STAGE_B(0, 0, 0, 0); STAGE_B(0, 0, 1, 0); STAGE_B(0, 1, 0, 0); STAGE_B(0, 1, 1, 0);
  STAGE_A(1, 0, 0, 1); STAGE_A(1, 0, 1, 1); STAGE_A(1, 1, 0, 1); STAGE_A(1, 1, 1, 1);
  STAGE_B(1, 0, 0, 1); STAGE_B(1, 0, 1, 1); STAGE_B(1, 1, 0, 1); STAGE_B(1, 1, 1, 1);
  asm volatile("s_waitcnt vmcnt(8)" ::: "memory");  // tile 0 landed
  BAR();
  RD_B(bx, lds + boff)
  RD_A(xa0, xa1, xa2, xa3, lds + aoff, 0)

#define TILE_BODY(BC, BN) do { \
    const int p = t & 1, pn = p ^ 1; \
    const char* Ab  = lds + p  * 65536 + aoff; \
    const char* Abn = lds + pn * 65536 + aoff; \
    const char* Bbn = lds + pn * 65536 + boff; \
    /* phase 0: issue A1 -> Y; stage A(t+1) h0; compute quad0 (X, BC) */ \
    RD_A(ya0, ya1, ya2, ya3, Ab, 1) \
    if (t > 0 && t + 1 < KT) { STAGE_A(t + 1, 0, 0, pn); STAGE_A(t + 1, 0, 1, pn); } \
    BAR(); \
    QUADM(0, xa0, xa1, xa2, xa3, BC) \
    BAR(); \
    /* phase 1: issue A2 -> X; stage A(t+1) h1; compute quad1 (Y, BC) */ \
    RD_A(xa0, xa1, xa2, xa3, Ab, 2) \
    if (t > 0 && t + 1 < KT) { STAGE_A(t + 1, 1, 0, pn); STAGE_A(t + 1, 1, 1, pn); } \
    BAR(); \
    QUADM(1, ya0, ya1, ya2, ya3, BC) \
    BAR(); \
    /* phase 2: issue A3 -> Y; stage B(t+2) h0; compute quad2 (X, BC) */ \
    RD_A(ya0, ya1, ya2, ya3, Ab, 3) \
    if (t + 2 < KT) { STAGE_B(t + 2, 0, 0, p); STAGE_B(t + 2, 0, 1, p); } \
    BAR(); \
    QUADM(2, xa0, xa1, xa2, xa3, BC) \
    BAR(); \
    /* phase 3: stage B(t+2) h1; vmcnt; BAR; prefetch next tile B + A0 -> X,BN; quad3 (Y, BC) */ \
    if (t + 2 < KT) { STAGE_B(t + 2, 1, 0, p); STAGE_B(t + 2, 1, 1, p); } \
    if (t < KT - 2)       asm volatile("s_waitcnt vmcnt(4)" ::: "memory"); \
    else if (t == KT - 2) asm volatile("s_waitcnt vmcnt(0)" ::: "memory"); \
    BAR(); \
    if (t + 1 < KT) { RD_A(xa0, xa1, xa2, xa3, Abn, 0) RD_B(BN, Bbn) } \
    QUADM(3, ya0, ya1, ya2, ya3, BC) \
    BAR(); \
  } while (0)

  for (int tt = 0; tt < KT; tt += 2) {
    int t = tt;
    TILE_BODY(bx, by);
    t = tt + 1;
    TILE_BODY(by, bx);
  }

  // ---- epilogue: C/D layout col=lane&15, row=(lane>>4)*4+reg ------------
  const int crow0 = tm * 256 + wr * 128 + ((lane >> 4) << 2);
  const int ccol0 = tn * 256 + wc * 64 + (lane & 15);
#pragma unroll
  for (int ni = 0; ni < 4; ++ni) {
    const float bv = bias[ccol0 + ni * 16];
#pragma unroll
    for (int mi = 0; mi < 8; ++mi) {
#pragma unroll
      for (int r = 0; r < 4; ++r) {
        C[(size_t)(crow0 + mi * 16 + r) * N_DIM + ccol0 + ni * 16] =
            acc[mi][ni][r] + bv;
      }
    }
  }
}

extern "C" void kernel_launch(void* const* d_in, const int* in_sizes, int n_in,
                              void* d_out, int out_size, void* d_ws, size_t ws_size,
                              hipStream_t stream) {
  const float* x    = (const float*)d_in[0];
  const int*   wq   = (const int*)d_in[1];
  const float* wsc  = (const float*)d_in[2];
  const float* bias = (const float*)d_in[3];
  float* out = (float*)d_out;

  const size_t xb_bytes = (size_t)M_DIM * K_DIM * 2;  // 64 MB
  const size_t wb_bytes = (size_t)N_DIM * K_DIM * 2;  // 128 MB
  if (ws_size < xb_bytes + wb_bytes) return;

  u16* xb = (u16*)d_ws;
  u16* wb = (u16*)((char*)d_ws + xb_bytes);

  cvt_x_kernel<<<2048, 256, 0, stream>>>(x, xb, M_DIM * K_DIM / 8);
  dequant_w_kernel<<<2048, 256, 0, stream>>>(wq, wsc, wb, N_DIM * K_DIM / 8);
  gemm_kernel<<<(M_DIM / 256) * (N_DIM / 256), 512, 0, stream>>>(xb, wb, bias, out);
}

// Round 4
// 1110.559 us; speedup vs baseline: 2.0206x; 2.0206x over previous
//
#include <hip/hip_runtime.h>

#define M_DIM 8192
#define K_DIM 4096
#define N_DIM 16384
#define KT 64   // K_DIM / 64 K-tiles

typedef unsigned short u16;
typedef __attribute__((ext_vector_type(8))) unsigned short ushort8;
typedef __attribute__((ext_vector_type(8))) short short8;
typedef __attribute__((ext_vector_type(4))) float f32x4;

// fp32 -> bf16 round-to-nearest-even
__device__ __forceinline__ u16 f2b(float f) {
  union { float f; unsigned u; } v; v.f = f;
  unsigned r = (v.u + 0x7fffu + ((v.u >> 16) & 1u)) >> 16;
  return (u16)r;
}

// ---- pre-pass 1: x fp32 -> bf16 ------------------------------------------
__global__ void cvt_x_kernel(const float* __restrict__ x, u16* __restrict__ xb, int n8) {
  int i = blockIdx.x * blockDim.x + threadIdx.x;
  const int stride = gridDim.x * blockDim.x;
  const float4* xf = reinterpret_cast<const float4*>(x);
  ushort8* o = reinterpret_cast<ushort8*>(xb);
  for (; i < n8; i += stride) {
    float4 a = xf[2 * i], b = xf[2 * i + 1];
    ushort8 r;
    r[0] = f2b(a.x); r[1] = f2b(a.y); r[2] = f2b(a.z); r[3] = f2b(a.w);
    r[4] = f2b(b.x); r[5] = f2b(b.y); r[6] = f2b(b.z); r[7] = f2b(b.w);
    o[i] = r;
  }
}

// ---- pre-pass 2: w_q int32 * block scale -> bf16 -------------------------
__global__ void dequant_w_kernel(const int* __restrict__ wq, const float* __restrict__ wsc,
                                 u16* __restrict__ wb, int n8) {
  int i = blockIdx.x * blockDim.x + threadIdx.x;
  const int stride = gridDim.x * blockDim.x;
  const int4* q = reinterpret_cast<const int4*>(wq);
  ushort8* o = reinterpret_cast<ushort8*>(wb);
  for (; i < n8; i += stride) {
    int n = i >> 9;
    int k8 = i & 511;
    float s = wsc[(n >> 7) * (K_DIM / 128) + (k8 >> 4)];
    int4 a = q[2 * i], b = q[2 * i + 1];
    ushort8 r;
    r[0] = f2b((float)a.x * s); r[1] = f2b((float)a.y * s);
    r[2] = f2b((float)a.z * s); r[3] = f2b((float)a.w * s);
    r[4] = f2b((float)b.x * s); r[5] = f2b((float)b.y * s);
    r[6] = f2b((float)b.z * s); r[7] = f2b((float)b.w * s);
    o[i] = r;
  }
}

// ---- async global -> LDS, 16 B per lane (dest = wave base + lane*16) -----
__device__ __forceinline__ void gload16(const void* g, void* l) {
  __builtin_amdgcn_global_load_lds(
      (const __attribute__((address_space(1))) unsigned int*)g,
      (__attribute__((address_space(3))) unsigned int*)l, 16, 0, 0);
}

#define BAR() do { asm volatile("" ::: "memory"); \
                   __builtin_amdgcn_s_barrier();  \
                   asm volatile("" ::: "memory"); } while (0)

#define MF(a, b, c) __builtin_amdgcn_mfma_f32_16x16x32_bf16(a, b, c, 0, 0, 0)

// ---- 256x256x64 8-wave GEMM, B-frag double-banked ------------------------
// Phase q: read A-quad q (4 ds_read), stage, barrier, 16 MFMA, barrier.
// Next tile's 8 B-frags are read at phase 3 AFTER vmcnt(4)+barrier (B(t+1)
// proven landed) and BEFORE the MFMAs, so their LDS service overlaps the
// QUAD(3) MFMA burst (compiler emits counted lgkmcnt: QUAD(3) only needs A3).
__global__ __launch_bounds__(512, 2) void gemm_kernel(
    const u16* __restrict__ A, const u16* __restrict__ B,
    const float* __restrict__ bias, float* __restrict__ C) {
  __shared__ __align__(128) char lds[131072];  // 2 bufs x (A 32K + B 32K)

  const int tid = threadIdx.x;
  const int lane = tid & 63, wid = tid >> 6;
  const int wr = wid >> 2, wc = wid & 3;    // 2 x 4 wave grid

  // XCD-bijective swizzle: 2048 blocks, 8 XCDs, 256 per XCD
  const int bid = blockIdx.x;
  const int swz = (bid & 7) * 256 + (bid >> 3);
  const int tm = swz >> 6, tn = swz & 63;   // 32 x 64 tiles

  // staging: per-lane pre-swizzled global source, linear LDS dest
  const int srow = (wid << 3) + (lane >> 3);
  const int kswz = ((lane & 7) ^ ((lane >> 3) & 7)) << 3;
  const u16* aSrc = A + (size_t)(tm * 256 + srow) * K_DIM + kswz;
  const u16* bSrc = B + (size_t)(tn * 256 + srow) * K_DIM + kswz;
  const int ldst = wid << 10;

#define STAGE_A(tt, h, s, b) gload16(aSrc + (size_t)((h)*128 + (s)*64) * K_DIM + (size_t)(tt)*64, \
                                     lds + (b)*65536 + (h)*16384 + (s)*8192 + ldst)
#define STAGE_B(tt, h, s, b) gload16(bSrc + (size_t)((h)*128 + (s)*64) * K_DIM + (size_t)(tt)*64, \
                                     lds + (b)*65536 + 32768 + (h)*16384 + (s)*8192 + ldst)

  // fragment read addressing (swizzled)
  const int hi = lane >> 4, lo3 = lane & 7;
  const int ak0 = ((0 + hi) ^ lo3) << 4;   // kk elements 0..31, 16B units
  const int ak1 = ((4 + hi) ^ lo3) << 4;   // kk elements 32..63
  const int aoff = (wr * 128 + (lane & 15)) * 128;
  const int boff = 32768 + (wc * 64 + (lane & 15)) * 128;

#define RD_A(base, q) \
  fa0 = *(const short8*)((base) + (2*(q)    ) * 2048 + ak0); \
  fa1 = *(const short8*)((base) + (2*(q)    ) * 2048 + ak1); \
  fa2 = *(const short8*)((base) + (2*(q) + 1) * 2048 + ak0); \
  fa3 = *(const short8*)((base) + (2*(q) + 1) * 2048 + ak1);

#define RD_B(P, base) \
  P##00 = *(const short8*)((base) + 0 * 2048 + ak0); \
  P##01 = *(const short8*)((base) + 0 * 2048 + ak1); \
  P##10 = *(const short8*)((base) + 1 * 2048 + ak0); \
  P##11 = *(const short8*)((base) + 1 * 2048 + ak1); \
  P##20 = *(const short8*)((base) + 2 * 2048 + ak0); \
  P##21 = *(const short8*)((base) + 2 * 2048 + ak1); \
  P##30 = *(const short8*)((base) + 3 * 2048 + ak0); \
  P##31 = *(const short8*)((base) + 3 * 2048 + ak1);

// 16 MFMA, same-acc dep distance 8: kk0 for both m-rows, then kk1
#define QUADR(q, P) \
  __builtin_amdgcn_s_setprio(1); \
  acc[2*(q)][0]   = MF(fa0, P##00, acc[2*(q)][0]); \
  acc[2*(q)][1]   = MF(fa0, P##10, acc[2*(q)][1]); \
  acc[2*(q)][2]   = MF(fa0, P##20, acc[2*(q)][2]); \
  acc[2*(q)][3]   = MF(fa0, P##30, acc[2*(q)][3]); \
  acc[2*(q)+1][0] = MF(fa2, P##00, acc[2*(q)+1][0]); \
  acc[2*(q)+1][1] = MF(fa2, P##10, acc[2*(q)+1][1]); \
  acc[2*(q)+1][2] = MF(fa2, P##20, acc[2*(q)+1][2]); \
  acc[2*(q)+1][3] = MF(fa2, P##30, acc[2*(q)+1][3]); \
  acc[2*(q)][0]   = MF(fa1, P##01, acc[2*(q)][0]); \
  acc[2*(q)][1]   = MF(fa1, P##11, acc[2*(q)][1]); \
  acc[2*(q)][2]   = MF(fa1, P##21, acc[2*(q)][2]); \
  acc[2*(q)][3]   = MF(fa1, P##31, acc[2*(q)][3]); \
  acc[2*(q)+1][0] = MF(fa3, P##01, acc[2*(q)+1][0]); \
  acc[2*(q)+1][1] = MF(fa3, P##11, acc[2*(q)+1][1]); \
  acc[2*(q)+1][2] = MF(fa3, P##21, acc[2*(q)+1][2]); \
  acc[2*(q)+1][3] = MF(fa3, P##31, acc[2*(q)+1][3]); \
  __builtin_amdgcn_s_setprio(0);

  f32x4 acc[8][4] = {};
  short8 fa0, fa1, fa2, fa3;   // single A bank (read+consume same phase)
  short8 bx00, bx01, bx10, bx11, bx20, bx21, bx30, bx31;  // B bank X
  short8 by00, by01, by10, by11, by20, by21, by30, by31;  // B bank Y

  // ---- prologue: stage tiles 0 (buf0) and 1 (buf1) ----------------------
  STAGE_A(0, 0, 0, 0); STAGE_A(0, 0, 1, 0); STAGE_A(0, 1, 0, 0); STAGE_A(0, 1, 1, 0);
  STAGE_B(0, 0, 0, 0); STAGE_B(0, 0, 1, 0); STAGE_B(0, 1, 0, 0); STAGE_B(0, 1, 1, 0);
  STAGE_A(1, 0, 0, 1); STAGE_A(1, 0, 1, 1); STAGE_A(1, 1, 0, 1); STAGE_A(1, 1, 1, 1);
  STAGE_B(1, 0, 0, 1); STAGE_B(1, 0, 1, 1); STAGE_B(1, 1, 0, 1); STAGE_B(1, 1, 1, 1);
  asm volatile("s_waitcnt vmcnt(8)" ::: "memory");  // tile 0 landed
  BAR();
  RD_B(bx, lds + boff)     // B(0) frags

#define TILE_BODY(BC, BN) do { \
    const int p = t & 1, pn = p ^ 1; \
    const char* Ab  = lds + p  * 65536 + aoff; \
    const char* Bbn = lds + pn * 65536 + boff; \
    /* phase 0 */ \
    RD_A(Ab, 0) \
    if (t > 0 && t + 1 < KT) { STAGE_A(t + 1, 0, 0, pn); STAGE_A(t + 1, 0, 1, pn); } \
    BAR(); \
    QUADR(0, BC) \
    BAR(); \
    /* phase 1 */ \
    RD_A(Ab, 1) \
    if (t > 0 && t + 1 < KT) { STAGE_A(t + 1, 1, 0, pn); STAGE_A(t + 1, 1, 1, pn); } \
    BAR(); \
    QUADR(1, BC) \
    BAR(); \
    /* phase 2 */ \
    RD_A(Ab, 2) \
    if (t + 2 < KT) { STAGE_B(t + 2, 0, 0, p); STAGE_B(t + 2, 0, 1, p); } \
    BAR(); \
    QUADR(2, BC) \
    BAR(); \
    /* phase 3: vmcnt, BAR, prefetch next-tile B frags, then MFMA (needs A3 only) */ \
    RD_A(Ab, 3) \
    if (t + 2 < KT) { STAGE_B(t + 2, 1, 0, p); STAGE_B(t + 2, 1, 1, p); } \
    if (t < KT - 2)       asm volatile("s_waitcnt vmcnt(4)" ::: "memory"); \
    else if (t == KT - 2) asm volatile("s_waitcnt vmcnt(0)" ::: "memory"); \
    BAR(); \
    if (t + 1 < KT) { RD_B(BN, Bbn) } \
    QUADR(3, BC) \
    BAR(); \
  } while (0)

  for (int tt = 0; tt < KT; tt += 2) {
    int t = tt;
    TILE_BODY(bx, by);
    t = tt + 1;
    TILE_BODY(by, bx);
  }

  // ---- epilogue: C/D layout col=lane&15, row=(lane>>4)*4+reg ------------
  const int crow0 = tm * 256 + wr * 128 + ((lane >> 4) << 2);
  const int ccol0 = tn * 256 + wc * 64 + (lane & 15);
#pragma unroll
  for (int ni = 0; ni < 4; ++ni) {
    const float bv = bias[ccol0 + ni * 16];
#pragma unroll
    for (int mi = 0; mi < 8; ++mi) {
#pragma unroll
      for (int r = 0; r < 4; ++r) {
        C[(size_t)(crow0 + mi * 16 + r) * N_DIM + ccol0 + ni * 16] =
            acc[mi][ni][r] + bv;
      }
    }
  }
}

extern "C" void kernel_launch(void* const* d_in, const int* in_sizes, int n_in,
                              void* d_out, int out_size, void* d_ws, size_t ws_size,
                              hipStream_t stream) {
  const float* x    = (const float*)d_in[0];
  const int*   wq   = (const int*)d_in[1];
  const float* wsc  = (const float*)d_in[2];
  const float* bias = (const float*)d_in[3];
  float* out = (float*)d_out;

  const size_t xb_bytes = (size_t)M_DIM * K_DIM * 2;  // 64 MB
  const size_t wb_bytes = (size_t)N_DIM * K_DIM * 2;  // 128 MB
  if (ws_size < xb_bytes + wb_bytes) return;

  u16* xb = (u16*)d_ws;
  u16* wb = (u16*)((char*)d_ws + xb_bytes);

  cvt_x_kernel<<<2048, 256, 0, stream>>>(x, xb, M_DIM * K_DIM / 8);
  dequant_w_kernel<<<2048, 256, 0, stream>>>(wq, wsc, wb, N_DIM * K_DIM / 8);
  gemm_kernel<<<(M_DIM / 256) * (N_DIM / 256), 512, 0, stream>>>(xb, wb, bias, out);
}